// Round 9
// baseline (97.275 us; speedup 1.0000x reference)
//
#include <hip/hip_runtime.h>
#include <stdint.h>

typedef __attribute__((ext_vector_type(8))) short bf16x8;
typedef __attribute__((ext_vector_type(4))) float f32x4;
typedef __attribute__((ext_vector_type(2))) float f32x2;

__device__ inline float bflo(uint32_t w) { union { uint32_t i; float f; } v; v.i = w << 16; return v.f; }
__device__ inline float bfhi(uint32_t w) { union { uint32_t i; float f; } v; v.i = w & 0xffff0000u; return v.f; }
__device__ inline uint32_t f2bf(float f) { union { float f; uint32_t i; } v; v.f = f; return (v.i + 0x8000u) >> 16; }
__device__ inline uint32_t pk(float lo, float hi) { return f2bf(lo) | (f2bf(hi) << 16); }

// packed 2xf32 add/sub (VOP3P), and packed f32->bf16 convert (gfx950)
__device__ inline f32x2 pka(f32x2 a, f32x2 b) {
    f32x2 d; asm("v_pk_add_f32 %0, %1, %2" : "=v"(d) : "v"(a), "v"(b)); return d;
}
__device__ inline f32x2 pks(f32x2 a, f32x2 b) {
    f32x2 d; asm("v_pk_add_f32 %0, %1, %2 neg_lo:[0,1] neg_hi:[0,1]" : "=v"(d) : "v"(a), "v"(b)); return d;
}
__device__ inline uint32_t cvtpk2(float lo, float hi) {
    uint32_t r; asm("v_cvt_pk_bf16_f32 %0, %1, %2" : "=v"(r) : "v"(lo), "v"(hi)); return r;
}
__device__ inline uint32_t cvtpk(f32x2 v) { return cvtpk2(v.x, v.y); }
__device__ inline f32x2 unpk(uint32_t w) {
    union { uint32_t u; float f; } lo, hi; lo.u = w << 16; hi.u = w & 0xffff0000u;
    return (f32x2){lo.f, hi.f};
}

// ---------------- Filter transform: U = G K G^T -> d_ws (bf16, frag-major) ----------------
// Layout (u16): U[pos=16][cblk=4][f=32][c7=8]; as u32: [pos][cblk*32+f][cpair2]
__global__ __launch_bounds__(256) void wg_filter(const float* __restrict__ Kk, uint32_t* __restrict__ Ud)
{
    const int idx = blockIdx.x * 256 + threadIdx.x;   // 0..511
    if (idx >= 512) return;
    const int cp = idx & 15, f = idx >> 4;
    float u[2][16];
    #pragma unroll
    for (int h = 0; h < 2; h++) {
        const float* kp = Kk + (f * 32 + cp * 2 + h) * 9;
        float k00 = kp[0], k01 = kp[1], k02 = kp[2];
        float k10 = kp[3], k11 = kp[4], k12 = kp[5];
        float k20 = kp[6], k21 = kp[7], k22 = kp[8];
        float t[4][3];
        t[0][0] = k00; t[0][1] = k01; t[0][2] = k02;
        t[1][0] = 0.5f * (k00 + k10 + k20); t[1][1] = 0.5f * (k01 + k11 + k21); t[1][2] = 0.5f * (k02 + k12 + k22);
        t[2][0] = 0.5f * (k00 - k10 + k20); t[2][1] = 0.5f * (k01 - k11 + k21); t[2][2] = 0.5f * (k02 - k12 + k22);
        t[3][0] = k20; t[3][1] = k21; t[3][2] = k22;
        #pragma unroll
        for (int i = 0; i < 4; i++) {
            float a0 = t[i][0], a1 = t[i][1], a2 = t[i][2];
            u[h][i * 4 + 0] = a0;
            u[h][i * 4 + 1] = 0.5f * (a0 + a1 + a2);
            u[h][i * 4 + 2] = 0.5f * (a0 - a1 + a2);
            u[h][i * 4 + 3] = a2;
        }
    }
    const int base = ((cp >> 2) * 32 + f) * 4 + (cp & 3);
    #pragma unroll
    for (int p = 0; p < 16; p++) Ud[p * 512 + base] = pk(u[0][p], u[1][p]);
}

// one Winograd chunk (B^T row I): per-lane in-register V fragment + 4 MFMAs + fold
template<int I>
__device__ __forceinline__ void wg_chunk(const uint32_t* __restrict__ pbase,
                                         const uint16_t* __restrict__ Ub,
                                         float (&y)[4][4])
{
    const int ra = (I == 0) ? 0 : (I == 2) ? 2 : 1;
    const int rb = (I == 3) ? 3 : (I == 2) ? 1 : 2;

    bf16x8 a_reg[4];
    #pragma unroll
    for (int l = 0; l < 4; l++)
        a_reg[l] = *(const bf16x8*)(Ub + (I * 4 + l) * 1024);

    uint32_t va[4][4];
    #pragma unroll
    for (int pp = 0; pp < 4; pp++) {
        const uint32_t* pr_ = pbase + pp * 182;
        uint2 wa0 = *(const uint2*)(pr_ + ra * 18);
        uint2 wa1 = *(const uint2*)(pr_ + ra * 18 + 2);
        uint2 wb0 = *(const uint2*)(pr_ + rb * 18);
        uint2 wb1 = *(const uint2*)(pr_ + rb * 18 + 2);
        f32x2 da0 = unpk(wa0.x), da1 = unpk(wa0.y), da2 = unpk(wa1.x), da3 = unpk(wa1.y);
        f32x2 db0 = unpk(wb0.x), db1 = unpk(wb0.y), db2 = unpk(wb1.x), db3 = unpk(wb1.y);
        f32x2 e0, e1, e2, e3;
        if (I == 1) {
            e0 = pka(da0, db0); e1 = pka(da1, db1); e2 = pka(da2, db2); e3 = pka(da3, db3);
        } else {
            e0 = pks(da0, db0); e1 = pks(da1, db1); e2 = pks(da2, db2); e3 = pks(da3, db3);
        }
        va[0][pp] = cvtpk(pks(e0, e2));
        va[1][pp] = cvtpk(pka(e1, e2));
        va[2][pp] = cvtpk(pks(e2, e1));
        va[3][pp] = cvtpk(pks(e1, e3));
    }

    f32x4 acc[4];
    #pragma unroll
    for (int l = 0; l < 4; l++) {
        union { uint32_t u[4]; bf16x8 v; } cvt;
        cvt.u[0] = va[l][0]; cvt.u[1] = va[l][1];
        cvt.u[2] = va[l][2]; cvt.u[3] = va[l][3];
        acc[l] = __builtin_amdgcn_mfma_f32_16x16x32_bf16(a_reg[l], cvt.v,
                    (f32x4){0.f, 0.f, 0.f, 0.f}, 0, 0, 0);
    }

    #pragma unroll
    for (int r = 0; r < 4; r++) {
        float m0 = acc[0][r], m1 = acc[1][r], m2 = acc[2][r], m3 = acc[3][r];
        float c0 = m0 + m1 + m2, c1 = m1 - m2 - m3;
        if (I == 0)      { y[r][0] += c0; y[r][1] += c1; }
        else if (I == 1) { y[r][0] += c0; y[r][1] += c1; y[r][2] += c0; y[r][3] += c1; }
        else if (I == 2) { y[r][0] += c0; y[r][1] += c1; y[r][2] -= c0; y[r][3] -= c1; }
        else             { y[r][2] -= c0; y[r][3] -= c1; }
    }
}

// ---------------- Main fused kernel: persistent blocks, 4 items, dbuf patch ----------------
// Grid 2048 x 256 threads. Each block: 4 work items; patch double-buffered in LDS
// (2 x 11648 B = 23296 -> 6 blocks/CU); next item's X loads issued before current
// item's compute (T14 issue-early/write-late). One barrier per item.
__global__ __launch_bounds__(256, 3) void wg_main(
    const float* __restrict__ X, const uint16_t* __restrict__ U, float* __restrict__ out)
{
    __shared__ __align__(16) uint32_t Pl[2][2912];

    const int tid = threadIdx.x;
    // XCD-chunked bijective swizzle (2048 % 8 == 0); 4 consecutive works per block.
    const int swz = (blockIdx.x & 7) * 256 + (blockIdx.x >> 3);
    const int wbase = swz * 4;

    const int wave = tid >> 6, lane = tid & 63;
    const int fh = wave & 1, tb = wave >> 1;
    const int l15 = lane & 15, lq = lane >> 4;
    const uint16_t* Ub = U + (lq * 32 + fh * 16 + l15) * 8;
    const int tt = tb * 16 + l15;
    const int trr = tt >> 3, tcc = tt & 7;
    const int lofs = (lq * 4) * 182 + (trr * 2) * 18 + tcc * 2;

    float2 Ar[3], Cr[3];

    // ---- prologue: stage item 0 into Pl[0] ----
    {
        const int w0 = wbase;
        const int qb = w0 & 15, pb = (w0 >> 4) & 31, bb = w0 >> 9;
        #pragma unroll
        for (int half = 0; half < 2; half++) {
            #pragma unroll
            for (int t = 0; t < 3; t++) {
                const int s = tid + (half * 3 + t) * 256;
                if (s < 1440) {
                    const int pr = s / 90, r = s - pr * 90, row = r / 9, seg = r - row * 9;
                    const float* g0 = X + ((size_t)((bb * 32 + pr * 2) * 258 + pb * 8 + row)) * 258 + qb * 16 + seg * 2;
                    Ar[t] = *(const float2*)g0;
                    Cr[t] = *(const float2*)(g0 + 66564);
                }
            }
            #pragma unroll
            for (int t = 0; t < 3; t++) {
                const int s = tid + (half * 3 + t) * 256;
                if (s < 1440) {
                    const int pr = s / 90, r = s - pr * 90, row = r / 9, seg = r - row * 9;
                    uint2 w; w.x = cvtpk2(Ar[t].x, Cr[t].x); w.y = cvtpk2(Ar[t].y, Cr[t].y);
                    *(uint2*)&Pl[0][pr * 182 + row * 18 + seg * 2] = w;
                }
            }
        }
    }
    __syncthreads();

    // ---- item loop ----
    #pragma unroll
    for (int k = 0; k < 4; ++k) {
        const int work = wbase + k;
        const int qb = work & 15, pb = (work >> 4) & 31, bb = work >> 9;
        const int wn = work + 1;
        const int qn = wn & 15, pn = (wn >> 4) & 31, bn = wn >> 9;
        const int nbuf = (k + 1) & 1;

        // issue first half of next item's loads (hidden under chunks 0-1)
        if (k < 3) {
            #pragma unroll
            for (int t = 0; t < 3; t++) {
                const int s = tid + t * 256;
                const int pr = s / 90, r = s - pr * 90, row = r / 9, seg = r - row * 9;
                const float* g0 = X + ((size_t)((bn * 32 + pr * 2) * 258 + pn * 8 + row)) * 258 + qn * 16 + seg * 2;
                Ar[t] = *(const float2*)g0;
                Cr[t] = *(const float2*)(g0 + 66564);
            }
        }

        const uint32_t* pbase = &Pl[k & 1][lofs];
        float y[4][4];
        #pragma unroll
        for (int r = 0; r < 4; r++)
            #pragma unroll
            for (int j = 0; j < 4; j++) y[r][j] = 0.f;

        wg_chunk<0>(pbase, Ub, y);
        wg_chunk<1>(pbase, Ub, y);

        // write half 1 of next patch; issue half 2 loads (hidden under chunks 2-3)
        if (k < 3) {
            #pragma unroll
            for (int t = 0; t < 3; t++) {
                const int s = tid + t * 256;
                const int pr = s / 90, r = s - pr * 90, row = r / 9, seg = r - row * 9;
                uint2 w; w.x = cvtpk2(Ar[t].x, Cr[t].x); w.y = cvtpk2(Ar[t].y, Cr[t].y);
                *(uint2*)&Pl[nbuf][pr * 182 + row * 18 + seg * 2] = w;
            }
            #pragma unroll
            for (int t = 0; t < 3; t++) {
                const int s = tid + (3 + t) * 256;
                if (s < 1440) {
                    const int pr = s / 90, r = s - pr * 90, row = r / 9, seg = r - row * 9;
                    const float* g0 = X + ((size_t)((bn * 32 + pr * 2) * 258 + pn * 8 + row)) * 258 + qn * 16 + seg * 2;
                    Ar[t] = *(const float2*)g0;
                    Cr[t] = *(const float2*)(g0 + 66564);
                }
            }
        }

        wg_chunk<2>(pbase, Ub, y);
        wg_chunk<3>(pbase, Ub, y);

        // store this item's output
        {
            const int p = pb * 4 + trr, q = qb * 8 + tcc;
            #pragma unroll
            for (int r = 0; r < 4; r++) {
                const int f = fh * 16 + lq * 4 + r;
                float* op = out + ((size_t)(bb * 32 + f) * 256 + 2 * p) * 256 + 2 * q;
                *(float2*)op = make_float2(y[r][0], y[r][1]);
                *(float2*)(op + 256) = make_float2(y[r][2], y[r][3]);
            }
        }

        // write half 2 of next patch
        if (k < 3) {
            #pragma unroll
            for (int t = 0; t < 3; t++) {
                const int s = tid + (3 + t) * 256;
                if (s < 1440) {
                    const int pr = s / 90, r = s - pr * 90, row = r / 9, seg = r - row * 9;
                    uint2 w; w.x = cvtpk2(Ar[t].x, Cr[t].x); w.y = cvtpk2(Ar[t].y, Cr[t].y);
                    *(uint2*)&Pl[nbuf][pr * 182 + row * 18 + seg * 2] = w;
                }
            }
        }
        __syncthreads();
    }
}

// ---------------- Fallback (monolithic) if ws is too small ----------------
__device__ inline uint16_t f2bf16_rne(float f) {
    union { float f; uint32_t i; } v; v.f = f;
    uint32_t x = v.i;
    uint32_t r = x + 0x7fffu + ((x >> 16) & 1u);
    return (uint16_t)(r >> 16);
}
__global__ __launch_bounds__(256) void winograd_fallback(
    const float* __restrict__ X, const float* __restrict__ K, float* __restrict__ out)
{
    __shared__ uint16_t Ul[16384];
    __shared__ uint16_t Vl[16384];
    __shared__ uint16_t Pl[32 * 242];
    const int tid = threadIdx.x;
    const int qb = blockIdx.x, pb = blockIdx.y, b = blockIdx.z;
    for (int idx = tid; idx < 1024; idx += 256) {
        const int f = idx >> 5, c = idx & 31;
        const float* kp = K + (f * 32 + c) * 9;
        float k00 = kp[0], k01 = kp[1], k02 = kp[2];
        float k10 = kp[3], k11 = kp[4], k12 = kp[5];
        float k20 = kp[6], k21 = kp[7], k22 = kp[8];
        float t[4][3];
        t[0][0] = k00; t[0][1] = k01; t[0][2] = k02;
        t[1][0] = 0.5f * (k00 + k10 + k20); t[1][1] = 0.5f * (k01 + k11 + k21); t[1][2] = 0.5f * (k02 + k12 + k22);
        t[2][0] = 0.5f * (k00 - k10 + k20); t[2][1] = 0.5f * (k01 - k11 + k21); t[2][2] = 0.5f * (k02 - k12 + k22);
        t[3][0] = k20; t[3][1] = k21; t[3][2] = k22;
        const int ubase = ((c >> 3) * 32 + f) * 8 + (c & 7);
        #pragma unroll
        for (int i = 0; i < 4; i++) {
            float a0 = t[i][0], a1 = t[i][1], a2 = t[i][2];
            Ul[(i * 4 + 0) * 1024 + ubase] = f2bf16_rne(a0);
            Ul[(i * 4 + 1) * 1024 + ubase] = f2bf16_rne(0.5f * (a0 + a1 + a2));
            Ul[(i * 4 + 2) * 1024 + ubase] = f2bf16_rne(0.5f * (a0 - a1 + a2));
            Ul[(i * 4 + 3) * 1024 + ubase] = f2bf16_rne(a2);
        }
    }
    const int y0 = pb * 8, x0 = qb * 16;
    for (int s = tid; s < 2880; s += 256) {
        const int c = s / 90;
        const int r = s % 90;
        const int row = r / 9, seg = r % 9;
        const float* gp = X + ((b * 32 + c) * 258 + (y0 + row)) * 258 + x0 + seg * 2;
        float2 g = *(const float2*)gp;
        uint32_t packed = (uint32_t)f2bf16_rne(g.x) | ((uint32_t)f2bf16_rne(g.y) << 16);
        *(uint32_t*)&Pl[c * 242 + row * 24 + seg * 2] = packed;
    }
    __syncthreads();
    for (int idx = tid; idx < 1024; idx += 256) {
        const int c = idx & 31, tt = idx >> 5;
        const int tr = tt >> 3, tc = tt & 7;
        const uint16_t* pp = &Pl[c * 242 + (tr * 2) * 24 + tc * 2];
        float d[4][4];
        #pragma unroll
        for (int j = 0; j < 4; j++) {
            uint32_t w0 = *(const uint32_t*)&pp[j * 24];
            uint32_t w1 = *(const uint32_t*)&pp[j * 24 + 2];
            d[j][0] = bflo(w0); d[j][1] = bfhi(w0);
            d[j][2] = bflo(w1); d[j][3] = bfhi(w1);
        }
        float bt[4][4];
        #pragma unroll
        for (int k = 0; k < 4; k++) {
            bt[0][k] = d[0][k] - d[2][k];
            bt[1][k] = d[1][k] + d[2][k];
            bt[2][k] = d[2][k] - d[1][k];
            bt[3][k] = d[1][k] - d[3][k];
        }
        const int vbase = (((tt >> 4) * 4 + (c >> 3)) * 16 + (tt & 15)) * 8 + (c & 7);
        #pragma unroll
        for (int i = 0; i < 4; i++) {
            float b0 = bt[i][0], b1 = bt[i][1], b2 = bt[i][2], b3 = bt[i][3];
            Vl[(i * 4 + 0) * 1024 + vbase] = f2bf16_rne(b0 - b2);
            Vl[(i * 4 + 1) * 1024 + vbase] = f2bf16_rne(b1 + b2);
            Vl[(i * 4 + 2) * 1024 + vbase] = f2bf16_rne(b2 - b1);
            Vl[(i * 4 + 3) * 1024 + vbase] = f2bf16_rne(b1 - b3);
        }
    }
    __syncthreads();
    const int wave = tid >> 6, lane = tid & 63;
    const int fh = wave & 1, tb = wave >> 1;
    const int l15 = lane & 15, lq = lane >> 4;
    f32x4 acc[16];
    #pragma unroll
    for (int p = 0; p < 16; p++) acc[p] = (f32x4){0.f, 0.f, 0.f, 0.f};
    #pragma unroll
    for (int p = 0; p < 16; p++) {
        bf16x8 a = *(const bf16x8*)&Ul[p * 1024 + (lq * 32 + fh * 16 + l15) * 8];
        bf16x8 bv = *(const bf16x8*)&Vl[p * 1024 + ((tb * 4 + lq) * 16 + l15) * 8];
        acc[p] = __builtin_amdgcn_mfma_f32_16x16x32_bf16(a, bv, acc[p], 0, 0, 0);
    }
    #pragma unroll
    for (int r = 0; r < 4; r++) {
        const int f = fh * 16 + lq * 4 + r;
        const int t = tb * 16 + l15;
        const int tr = t >> 3, tc = t & 7;
        const int p = pb * 4 + tr, q = qb * 8 + tc;
        float m[4][4];
        #pragma unroll
        for (int i = 0; i < 4; i++)
            #pragma unroll
            for (int l = 0; l < 4; l++)
                m[i][l] = acc[i * 4 + l][r];
        float s0[4], s1[4];
        #pragma unroll
        for (int k = 0; k < 4; k++) {
            s0[k] = m[0][k] + m[1][k] + m[2][k];
            s1[k] = m[1][k] - m[2][k] - m[3][k];
        }
        float* op = out + ((size_t)(b * 32 + f) * 256 + 2 * p) * 256 + 2 * q;
        *(float2*)op = make_float2(s0[0] + s0[1] + s0[2], s0[1] - s0[2] - s0[3]);
        *(float2*)(op + 256) = make_float2(s1[0] + s1[1] + s1[2], s1[1] - s1[2] - s1[3]);
    }
}

extern "C" void kernel_launch(void* const* d_in, const int* in_sizes, int n_in,
                              void* d_out, int out_size, void* d_ws, size_t ws_size,
                              hipStream_t stream) {
    const float* X = (const float*)d_in[0];
    const float* K = (const float*)d_in[1];
    float* out = (float*)d_out;
    if (ws_size >= 32768) {
        wg_filter<<<2, 256, 0, stream>>>(K, (uint32_t*)d_ws);
        wg_main<<<2048, 256, 0, stream>>>(X, (const uint16_t*)d_ws, out);
    } else {
        dim3 grid(16, 32, 16);
        winograd_fallback<<<grid, 256, 0, stream>>>(X, K, out);
    }
}

// Round 10
// 82.243 us; speedup vs baseline: 1.1828x; 1.1828x over previous
//
#include <hip/hip_runtime.h>
#include <stdint.h>

typedef __attribute__((ext_vector_type(8))) short bf16x8;
typedef __attribute__((ext_vector_type(4))) float f32x4;
typedef __attribute__((ext_vector_type(2))) float f32x2;

__device__ inline float bflo(uint32_t w) { union { uint32_t i; float f; } v; v.i = w << 16; return v.f; }
__device__ inline float bfhi(uint32_t w) { union { uint32_t i; float f; } v; v.i = w & 0xffff0000u; return v.f; }
__device__ inline uint32_t f2bf(float f) { union { float f; uint32_t i; } v; v.f = f; return (v.i + 0x8000u) >> 16; }
__device__ inline uint32_t pk(float lo, float hi) { return f2bf(lo) | (f2bf(hi) << 16); }

// packed 2xf32 add/sub (VOP3P), and packed f32->bf16 convert (gfx950)
__device__ inline f32x2 pka(f32x2 a, f32x2 b) {
    f32x2 d; asm("v_pk_add_f32 %0, %1, %2" : "=v"(d) : "v"(a), "v"(b)); return d;
}
__device__ inline f32x2 pks(f32x2 a, f32x2 b) {
    f32x2 d; asm("v_pk_add_f32 %0, %1, %2 neg_lo:[0,1] neg_hi:[0,1]" : "=v"(d) : "v"(a), "v"(b)); return d;
}
__device__ inline uint32_t cvtpk2(float lo, float hi) {
    uint32_t r; asm("v_cvt_pk_bf16_f32 %0, %1, %2" : "=v"(r) : "v"(lo), "v"(hi)); return r;
}
__device__ inline uint32_t cvtpk(f32x2 v) { return cvtpk2(v.x, v.y); }
__device__ inline f32x2 unpk(uint32_t w) {
    union { uint32_t u; float f; } lo, hi; lo.u = w << 16; hi.u = w & 0xffff0000u;
    return (f32x2){lo.f, hi.f};
}

// ---------------- Filter transform: U = G K G^T -> d_ws (bf16, frag-major) ----------------
// Layout (u16): U[pos=16][cblk=4][f=32][c7=8]; as u32: [pos][cblk*32+f][cpair2]
__global__ __launch_bounds__(256) void wg_filter(const float* __restrict__ Kk, uint32_t* __restrict__ Ud)
{
    const int idx = blockIdx.x * 256 + threadIdx.x;   // 0..511
    if (idx >= 512) return;
    const int cp = idx & 15, f = idx >> 4;
    float u[2][16];
    #pragma unroll
    for (int h = 0; h < 2; h++) {
        const float* kp = Kk + (f * 32 + cp * 2 + h) * 9;
        float k00 = kp[0], k01 = kp[1], k02 = kp[2];
        float k10 = kp[3], k11 = kp[4], k12 = kp[5];
        float k20 = kp[6], k21 = kp[7], k22 = kp[8];
        float t[4][3];
        t[0][0] = k00; t[0][1] = k01; t[0][2] = k02;
        t[1][0] = 0.5f * (k00 + k10 + k20); t[1][1] = 0.5f * (k01 + k11 + k21); t[1][2] = 0.5f * (k02 + k12 + k22);
        t[2][0] = 0.5f * (k00 - k10 + k20); t[2][1] = 0.5f * (k01 - k11 + k21); t[2][2] = 0.5f * (k02 - k12 + k22);
        t[3][0] = k20; t[3][1] = k21; t[3][2] = k22;
        #pragma unroll
        for (int i = 0; i < 4; i++) {
            float a0 = t[i][0], a1 = t[i][1], a2 = t[i][2];
            u[h][i * 4 + 0] = a0;
            u[h][i * 4 + 1] = 0.5f * (a0 + a1 + a2);
            u[h][i * 4 + 2] = 0.5f * (a0 - a1 + a2);
            u[h][i * 4 + 3] = a2;
        }
    }
    const int base = ((cp >> 2) * 32 + f) * 4 + (cp & 3);
    #pragma unroll
    for (int p = 0; p < 16; p++) Ud[p * 512 + base] = pk(u[0][p], u[1][p]);
}

// ---------------- Main fused kernel ----------------
// Block: 256 threads, 32 tiles (4 tile-rows x 8 tile-cols), 8192 blocks.
// R7 base + (1) U software pipeline: chunk i+1's A-fragments prefetched during
// chunk i (hides the ~200cy L2 hit), chunk 0's under the X staging; (2) V
// double-buffer: WAR barriers eliminated (5 barriers/block instead of 8).
// LDS 28032 B -> 5 blocks/CU; launch_bounds(256,3) -> 85-reg budget (demand ~75).
__global__ __launch_bounds__(256, 3) void wg_main(
    const float* __restrict__ X, const uint16_t* __restrict__ U, float* __restrict__ out)
{
    // packed channel-pair patch: Pl[pair=16][row=10][col=18] u32, plane stride 182
    __shared__ __align__(16) uint32_t Pl[2912];
    // V double-buffer: V[2][l=4][tblk=2][cblk=4][t15=16][c7=8] bf16, 2 x 8 KB
    __shared__ __align__(16) uint16_t Vl[2][4096];

    const int tid = threadIdx.x;
    // XCD-chunked bijective swizzle (8192 blocks % 8 == 0)
    const int lin  = blockIdx.x + 16 * (blockIdx.y + 32 * blockIdx.z);
    const int work = (lin & 7) * 1024 + (lin >> 3);
    const int qb = work & 15;          // tile col base qb*8
    const int pb = (work >> 4) & 31;   // tile row base pb*4
    const int b  = work >> 9;
    const int y0 = pb * 8, x0 = qb * 16;

    const int wave = tid >> 6, lane = tid & 63;
    const int fh = wave & 1, tb = wave >> 1;
    const int l15 = lane & 15, lq = lane >> 4;
    const uint16_t* Ub = U + (lq * 32 + fh * 16 + l15) * 8;

    // prefetch chunk 0's U fragments (latency hidden under X staging)
    bf16x8 a_cur[4];
    #pragma unroll
    for (int l = 0; l < 4; l++)
        a_cur[l] = *(const bf16x8*)(Ub + l * 1024);

    // ---- Phase B: stage 10x18 patch, channel pairs packed in u32 ----
    for (int s = tid; s < 1440; s += 256) {
        const int pr = s / 90;
        const int r  = s - pr * 90;
        const int row = r / 9, seg = r - row * 9;
        const float* g0 = X + ((size_t)((b * 32 + pr * 2) * 258 + y0 + row)) * 258 + x0 + seg * 2;
        float2 a = *(const float2*)g0;
        float2 c = *(const float2*)(g0 + 258 * 258);
        uint2 w;
        w.x = cvtpk2(a.x, c.x);
        w.y = cvtpk2(a.y, c.y);
        *(uint2*)&Pl[pr * 182 + row * 18 + seg * 2] = w;
    }
    __syncthreads();

    // per-thread C-phase indices (constant across chunks)
    const int cp2 = tid & 3, t15c = (tid >> 2) & 15;

    float y[4][4];
    #pragma unroll
    for (int r = 0; r < 4; r++)
        #pragma unroll
        for (int j = 0; j < 4; j++) y[r][j] = 0.f;

    // ---- Chunk loop over B^T rows i=0..3 (4 positions each) ----
    #pragma unroll
    for (int i = 0; i < 4; i++) {
        // rows (ra,rb) and op for bt_i: i0: d0-d2; i1: d1+d2; i2: d2-d1; i3: d1-d3
        const int ra = (i == 0) ? 0 : (i == 2) ? 2 : 1;
        const int rb = (i == 3) ? 3 : (i == 2) ? 1 : 2;

        uint32_t* vp = (uint32_t*)Vl[i & 1];

        // Phase C(i): V row i (4 positions) from 2 patch rows -> Vl[i&1]
        #pragma unroll
        for (int it = 0; it < 2; it++) {
            const int rem  = it * 4 + wave;
            const int tblk = rem & 1, cpH = rem >> 1;
            const int cp   = cpH * 4 + cp2;
            const int tt   = tblk * 16 + t15c;
            const int tr   = tt >> 3, tc = tt & 7;
            const uint32_t* pp = &Pl[cp * 182 + (tr * 2) * 18 + tc * 2];
            uint2 wa0 = *(const uint2*)&pp[ra * 18];
            uint2 wa1 = *(const uint2*)&pp[ra * 18 + 2];
            uint2 wb0 = *(const uint2*)&pp[rb * 18];
            uint2 wb1 = *(const uint2*)&pp[rb * 18 + 2];
            f32x2 da[4], db[4];
            da[0] = unpk(wa0.x); da[1] = unpk(wa0.y); da[2] = unpk(wa1.x); da[3] = unpk(wa1.y);
            db[0] = unpk(wb0.x); db[1] = unpk(wb0.y); db[2] = unpk(wb1.x); db[3] = unpk(wb1.y);
            f32x2 e[4];
            #pragma unroll
            for (int k = 0; k < 4; k++)
                e[k] = (i == 1) ? pka(da[k], db[k]) : pks(da[k], db[k]);
            const int vbase = ((tblk * 4 + cpH) * 16 + t15c) * 4 + cp2;
            vp[0 * 512 + vbase] = cvtpk(pks(e[0], e[2]));
            vp[1 * 512 + vbase] = cvtpk(pka(e[1], e[2]));
            vp[2 * 512 + vbase] = cvtpk(pks(e[2], e[1]));
            vp[3 * 512 + vbase] = cvtpk(pks(e[1], e[3]));
        }

        // prefetch next chunk's U fragments (latency hides under barrier + ds_reads)
        bf16x8 a_nxt[4];
        if (i < 3) {
            #pragma unroll
            for (int l = 0; l < 4; l++)
                a_nxt[l] = *(const bf16x8*)(Ub + ((i + 1) * 4 + l) * 1024);
        }

        __syncthreads();   // Vl[i&1] ready

        // Phase D(i): 4 MFMAs from Vl[i&1] with prefetched a_cur.
        // No WAR barrier needed: C(i+1) writes Vl[(i+1)&1] (other buffer), and
        // C(i+2)'s overwrite of this buffer is ordered by C(i+1)'s barrier.
        const uint16_t* Vb = Vl[i & 1] + ((tb * 4 + lq) * 16 + l15) * 8;
        f32x4 acc[4];
        #pragma unroll
        for (int l = 0; l < 4; l++) {
            bf16x8 v = *(const bf16x8*)(Vb + l * 1024);
            acc[l] = __builtin_amdgcn_mfma_f32_16x16x32_bf16(a_cur[l], v,
                        (f32x4){0.f, 0.f, 0.f, 0.f}, 0, 0, 0);
        }

        #pragma unroll
        for (int l = 0; l < 4; l++) a_cur[l] = a_nxt[l];

        // incremental A^T fold of this chunk (one B^T row i)
        #pragma unroll
        for (int r = 0; r < 4; r++) {
            float m0 = acc[0][r], m1 = acc[1][r], m2 = acc[2][r], m3 = acc[3][r];
            float c0 = m0 + m1 + m2, c1 = m1 - m2 - m3;
            if (i == 0)      { y[r][0] += c0; y[r][1] += c1; }
            else if (i == 1) { y[r][0] += c0; y[r][1] += c1; y[r][2] += c0; y[r][3] += c1; }
            else if (i == 2) { y[r][0] += c0; y[r][1] += c1; y[r][2] -= c0; y[r][3] -= c1; }
            else             { y[r][2] -= c0; y[r][3] -= c1; }
        }
    }

    // ---- Store ----
    const int tt = tb * 16 + l15;
    const int trr = tt >> 3, tcc = tt & 7;
    const int p = pb * 4 + trr, q = qb * 8 + tcc;
    #pragma unroll
    for (int r = 0; r < 4; r++) {
        const int f = fh * 16 + lq * 4 + r;
        float* op = out + ((size_t)(b * 32 + f) * 256 + 2 * p) * 256 + 2 * q;
        *(float2*)op = make_float2(y[r][0], y[r][1]);
        *(float2*)(op + 256) = make_float2(y[r][2], y[r][3]);
    }
}

// ---------------- Fallback (monolithic) if ws is too small ----------------
__device__ inline uint16_t f2bf16_rne(float f) {
    union { float f; uint32_t i; } v; v.f = f;
    uint32_t x = v.i;
    uint32_t r = x + 0x7fffu + ((x >> 16) & 1u);
    return (uint16_t)(r >> 16);
}
__global__ __launch_bounds__(256) void winograd_fallback(
    const float* __restrict__ X, const float* __restrict__ K, float* __restrict__ out)
{
    __shared__ uint16_t Ul[16384];
    __shared__ uint16_t Vl[16384];
    __shared__ uint16_t Pl[32 * 242];
    const int tid = threadIdx.x;
    const int qb = blockIdx.x, pb = blockIdx.y, b = blockIdx.z;
    for (int idx = tid; idx < 1024; idx += 256) {
        const int f = idx >> 5, c = idx & 31;
        const float* kp = K + (f * 32 + c) * 9;
        float k00 = kp[0], k01 = kp[1], k02 = kp[2];
        float k10 = kp[3], k11 = kp[4], k12 = kp[5];
        float k20 = kp[6], k21 = kp[7], k22 = kp[8];
        float t[4][3];
        t[0][0] = k00; t[0][1] = k01; t[0][2] = k02;
        t[1][0] = 0.5f * (k00 + k10 + k20); t[1][1] = 0.5f * (k01 + k11 + k21); t[1][2] = 0.5f * (k02 + k12 + k22);
        t[2][0] = 0.5f * (k00 - k10 + k20); t[2][1] = 0.5f * (k01 - k11 + k21); t[2][2] = 0.5f * (k02 - k12 + k22);
        t[3][0] = k20; t[3][1] = k21; t[3][2] = k22;
        const int ubase = ((c >> 3) * 32 + f) * 8 + (c & 7);
        #pragma unroll
        for (int i = 0; i < 4; i++) {
            float a0 = t[i][0], a1 = t[i][1], a2 = t[i][2];
            Ul[(i * 4 + 0) * 1024 + ubase] = f2bf16_rne(a0);
            Ul[(i * 4 + 1) * 1024 + ubase] = f2bf16_rne(0.5f * (a0 + a1 + a2));
            Ul[(i * 4 + 2) * 1024 + ubase] = f2bf16_rne(0.5f * (a0 - a1 + a2));
            Ul[(i * 4 + 3) * 1024 + ubase] = f2bf16_rne(a2);
        }
    }
    const int y0 = pb * 8, x0 = qb * 16;
    for (int s = tid; s < 2880; s += 256) {
        const int c = s / 90;
        const int r = s % 90;
        const int row = r / 9, seg = r % 9;
        const float* gp = X + ((b * 32 + c) * 258 + (y0 + row)) * 258 + x0 + seg * 2;
        float2 g = *(const float2*)gp;
        uint32_t packed = (uint32_t)f2bf16_rne(g.x) | ((uint32_t)f2bf16_rne(g.y) << 16);
        *(uint32_t*)&Pl[c * 242 + row * 24 + seg * 2] = packed;
    }
    __syncthreads();
    for (int idx = tid; idx < 1024; idx += 256) {
        const int c = idx & 31, tt = idx >> 5;
        const int tr = tt >> 3, tc = tt & 7;
        const uint16_t* pp = &Pl[c * 242 + (tr * 2) * 24 + tc * 2];
        float d[4][4];
        #pragma unroll
        for (int j = 0; j < 4; j++) {
            uint32_t w0 = *(const uint32_t*)&pp[j * 24];
            uint32_t w1 = *(const uint32_t*)&pp[j * 24 + 2];
            d[j][0] = bflo(w0); d[j][1] = bfhi(w0);
            d[j][2] = bflo(w1); d[j][3] = bfhi(w1);
        }
        float bt[4][4];
        #pragma unroll
        for (int k = 0; k < 4; k++) {
            bt[0][k] = d[0][k] - d[2][k];
            bt[1][k] = d[1][k] + d[2][k];
            bt[2][k] = d[2][k] - d[1][k];
            bt[3][k] = d[1][k] - d[3][k];
        }
        const int vbase = (((tt >> 4) * 4 + (c >> 3)) * 16 + (tt & 15)) * 8 + (c & 7);
        #pragma unroll
        for (int i = 0; i < 4; i++) {
            float b0 = bt[i][0], b1 = bt[i][1], b2 = bt[i][2], b3 = bt[i][3];
            Vl[(i * 4 + 0) * 1024 + vbase] = f2bf16_rne(b0 - b2);
            Vl[(i * 4 + 1) * 1024 + vbase] = f2bf16_rne(b1 + b2);
            Vl[(i * 4 + 2) * 1024 + vbase] = f2bf16_rne(b2 - b1);
            Vl[(i * 4 + 3) * 1024 + vbase] = f2bf16_rne(b1 - b3);
        }
    }
    __syncthreads();
    const int wave = tid >> 6, lane = tid & 63;
    const int fh = wave & 1, tb = wave >> 1;
    const int l15 = lane & 15, lq = lane >> 4;
    f32x4 acc[16];
    #pragma unroll
    for (int p = 0; p < 16; p++) acc[p] = (f32x4){0.f, 0.f, 0.f, 0.f};
    #pragma unroll
    for (int p = 0; p < 16; p++) {
        bf16x8 a = *(const bf16x8*)&Ul[p * 1024 + (lq * 32 + fh * 16 + l15) * 8];
        bf16x8 bv = *(const bf16x8*)&Vl[p * 1024 + ((tb * 4 + lq) * 16 + l15) * 8];
        acc[p] = __builtin_amdgcn_mfma_f32_16x16x32_bf16(a, bv, acc[p], 0, 0, 0);
    }
    #pragma unroll
    for (int r = 0; r < 4; r++) {
        const int f = fh * 16 + lq * 4 + r;
        const int t = tb * 16 + l15;
        const int tr = t >> 3, tc = t & 7;
        const int p = pb * 4 + tr, q = qb * 8 + tc;
        float m[4][4];
        #pragma unroll
        for (int i = 0; i < 4; i++)
            #pragma unroll
            for (int l = 0; l < 4; l++)
                m[i][l] = acc[i * 4 + l][r];
        float s0[4], s1[4];
        #pragma unroll
        for (int k = 0; k < 4; k++) {
            s0[k] = m[0][k] + m[1][k] + m[2][k];
            s1[k] = m[1][k] - m[2][k] - m[3][k];
        }
        float* op = out + ((size_t)(b * 32 + f) * 256 + 2 * p) * 256 + 2 * q;
        *(float2*)op = make_float2(s0[0] + s0[1] + s0[2], s0[1] - s0[2] - s0[3]);
        *(float2*)(op + 256) = make_float2(s1[0] + s1[1] + s1[2], s1[1] - s1[2] - s1[3]);
    }
}

extern "C" void kernel_launch(void* const* d_in, const int* in_sizes, int n_in,
                              void* d_out, int out_size, void* d_ws, size_t ws_size,
                              hipStream_t stream) {
    const float* X = (const float*)d_in[0];
    const float* K = (const float*)d_in[1];
    float* out = (float*)d_out;
    dim3 grid(16, 32, 16);
    if (ws_size >= 32768) {
        wg_filter<<<2, 256, 0, stream>>>(K, (uint32_t*)d_ws);
        wg_main<<<grid, 256, 0, stream>>>(X, (const uint16_t*)d_ws, out);
    } else {
        winograd_fallback<<<grid, 256, 0, stream>>>(X, K, out);
    }
}